// Round 6
// baseline (411.355 us; speedup 1.0000x reference)
//
#include <hip/hip_runtime.h>

#define NPTS 65536

typedef __bf16 bf16_t;
typedef __bf16 bf16x8 __attribute__((ext_vector_type(8)));
typedef float f32x16 __attribute__((ext_vector_type(16)));

__device__ __forceinline__ float relu(float v) { return v > 0.f ? v : 0.f; }

// Fragment-major layouts (the contract between producers and consumers):
// Activation X (K ch), 128-pt block b, k-chunk c (64 k): elem idx =
//   (b*(K/64)+c)*8192 + ((s*4+mi)*64 + lane)*8 + j
//   where point p = b*128 + mi*32 + (lane&31), k = c*64 + s*16 + (lane>>5)*8 + j.
// Weight W (N x K), col-strip st (32 ch): elem idx =
//   ((st*(K/64)+c)*4+s)*512 + lane*8 + j
//   where n = st*32 + (lane&31), k = c*64 + s*16 + (lane>>5)*8 + j.

// ============ kprep: pack fp32 weights into hi/lo bf16 B-fragment order
struct PrepSeg { const float* src; bf16_t* h; bf16_t* l; int SW; int K; int nblk; };
struct PrepAll { PrepSeg seg[6]; };

__global__ __launch_bounds__(256) void kprep(PrepAll pa) {
  int blk = blockIdx.x, i = 0;
  while (blk >= pa.seg[i].nblk) { blk -= pa.seg[i].nblk; ++i; }
  const PrepSeg sg = pa.seg[i];
  int t8 = blk * 256 + threadIdx.x;
  int lane = t8 & 63;
  int rest = t8 >> 6;
  int s = rest & 3; rest >>= 2;
  int KC6 = sg.K >> 6;
  int c = rest % KC6, st = rest / KC6;
  int n = st * 32 + (lane & 31);
  int k0 = c * 64 + s * 16 + (lane >> 5) * 8;
  const float* src = sg.src + (size_t)n * sg.SW + k0;
  bf16x8 hv, lv;
#pragma unroll
  for (int j = 0; j < 8; ++j) {
    float v = src[j];
    bf16_t h = (bf16_t)v;
    hv[j] = h; lv[j] = (bf16_t)(v - (float)h);
  }
  *(bf16x8*)(sg.h + (size_t)t8 * 8) = hv;
  *(bf16x8*)(sg.l + (size_t)t8 * 8) = lv;
}

// ============ k1a: h1 = relu(x@W1.T+b1), written directly in A-fragment order
__global__ __launch_bounds__(256, 2) void k1a(
    const float* __restrict__ x, const float* __restrict__ W1, const float* __restrict__ b1,
    bf16_t* __restrict__ h1h, bf16_t* __restrict__ h1l) {
  int p = blockIdx.x * 256 + threadIdx.x;
  float x0 = x[p * 3 + 0], x1 = x[p * 3 + 1], x2 = x[p * 3 + 2];
  int b = p >> 7, mi = (p >> 5) & 3, lr = p & 31;
#pragma unroll
  for (int s = 0; s < 4; ++s)
#pragma unroll
    for (int hf = 0; hf < 2; ++hf) {
      bf16x8 hv, lv;
#pragma unroll
      for (int j = 0; j < 8; ++j) {
        int c = s * 16 + hf * 8 + j;
        float v = relu(fmaf(W1[c * 3], x0, fmaf(W1[c * 3 + 1], x1, fmaf(W1[c * 3 + 2], x2, b1[c]))));
        bf16_t h = (bf16_t)v;
        hv[j] = h; lv[j] = (bf16_t)(v - (float)h);
      }
      size_t off = (size_t)b * 8192 + (size_t)((s * 4 + mi) * 64 + hf * 32 + lr) * 8;
      *(bf16x8*)(h1h + off) = hv;
      *(bf16x8*)(h1l + off) = lv;
    }
}

// ============ gemmF: C[p][n] = act(A·W + bias), 3-term split via 32x32x16 bf16 MFMA.
// RB row-blocks of 128 pts; NWC=4/RB waves on cols, NI strips of 32 ch per wave.
// A staged in LDS (frag-major: contiguous copy, conflict-free); B loaded global->reg.
// MODE 0: store frag-pair output. MODE 1: fused point-max -> aux. MODE 2: fused dot w8 -> aux.
template <int RB, int NI, int K, int MODE>
__global__ __launch_bounds__(256, 2) void gemmF(
    const bf16_t* __restrict__ Ah, const bf16_t* __restrict__ Al,
    const bf16_t* __restrict__ Bh, const bf16_t* __restrict__ Bl,
    const float* __restrict__ bias,
    bf16_t* __restrict__ Oh, bf16_t* __restrict__ Ol,
    float* __restrict__ aux, const float* __restrict__ w8, const float* __restrict__ b8) {
  constexpr int NWC = 4 / RB;
  constexpr int NC = K / 64;
  constexpr int DB = (NC > 1) ? 2 : 1;
  constexpr int NBLK = NWC * NI * 32;
  constexpr int STAGE = RB * DB * 32768;
  constexpr int SMEM = (MODE == 0 && STAGE < 36864) ? 36864 : STAGE;
  __shared__ char smem[SMEM];

  int tid = threadIdx.x;
  int lane = tid & 63;
  int w = __builtin_amdgcn_readfirstlane(tid >> 6);
  int rgrp = w / NWC, cw = w % NWC;
  int st0 = blockIdx.y * (NWC * NI) + cw * NI;

  f32x16 acc[4][NI];
#pragma unroll
  for (int ni = 0; ni < NI; ++ni) {
    float bv = bias[(st0 + ni) * 32 + (lane & 31)];
#pragma unroll
    for (int mi = 0; mi < 4; ++mi)
#pragma unroll
      for (int r = 0; r < 16; ++r) acc[mi][ni][r] = bv;
  }

  auto stage = [&](int buf, int c) {
#pragma unroll
    for (int i = 0; i < RB * 8; ++i) {
      int o = (i * 256 + tid) * 16;          // byte offset in [0, RB*32768)
      int rgs = o >> 15;
      int rem = o & 32767;
      int kind = rem >> 14;
      int inner = rem & 16383;               // bytes within 16KB region
      const bf16_t* src = (kind ? Al : Ah) +
          ((size_t)(blockIdx.x * RB + rgs) * NC + c) * 8192 + (inner >> 1);
      char* dst = smem + (size_t)((buf * RB + rgs) * 2 + kind) * 16384 + inner;
      *(bf16x8*)dst = *(const bf16x8*)src;
    }
  };

  auto compute = [&](int buf, int c) {
    const char* base = smem + (size_t)((buf * RB + rgrp) * 2) * 16384;
    const bf16_t* pAh = (const bf16_t*)base;
    const bf16_t* pAl = (const bf16_t*)(base + 16384);
#pragma unroll
    for (int s = 0; s < 4; ++s) {
      bf16x8 bhf[NI], blf[NI];
#pragma unroll
      for (int ni = 0; ni < NI; ++ni) {
        size_t bo = ((size_t)((st0 + ni) * NC + c) * 4 + s) * 512 + lane * 8;
        bhf[ni] = *(const bf16x8*)(Bh + bo);
        blf[ni] = *(const bf16x8*)(Bl + bo);
      }
#pragma unroll
      for (int mi = 0; mi < 4; ++mi) {
        int fo = ((s * 4 + mi) * 64 + lane) * 8;
        bf16x8 ah = *(const bf16x8*)(pAh + fo);
        bf16x8 al = *(const bf16x8*)(pAl + fo);
#pragma unroll
        for (int ni = 0; ni < NI; ++ni) {
          acc[mi][ni] = __builtin_amdgcn_mfma_f32_32x32x16_bf16(ah, bhf[ni], acc[mi][ni], 0, 0, 0);
          acc[mi][ni] = __builtin_amdgcn_mfma_f32_32x32x16_bf16(al, bhf[ni], acc[mi][ni], 0, 0, 0);
          acc[mi][ni] = __builtin_amdgcn_mfma_f32_32x32x16_bf16(ah, blf[ni], acc[mi][ni], 0, 0, 0);
        }
      }
    }
  };

  stage(0, 0);
  for (int c = 0; c < NC; ++c) {
    __syncthreads();
    if (c + 1 < NC) stage((c + 1) & 1, c + 1);
    compute(c % DB, c);
  }

  if constexpr (MODE == 0) {
    __syncthreads();
    bf16_t (*sTh)[72] = (bf16_t (*)[72])smem;
    bf16_t (*sTl)[72] = (bf16_t (*)[72])(smem + 128 * 72 * 2);
    constexpr int NCC = NBLK / 64;
    int KOc = (gridDim.y * NBLK) >> 6;
    for (int rge = 0; rge < RB; ++rge)
      for (int cc = 0; cc < NCC; ++cc) {
        if (rgrp == rge) {
#pragma unroll
          for (int ni = 0; ni < NI; ++ni) {
            int stl = cw * NI + ni;
            if ((stl >> 1) == cc) {
              int ncol = (stl & 1) * 32 + (lane & 31);
#pragma unroll
              for (int mi = 0; mi < 4; ++mi)
#pragma unroll
                for (int r = 0; r < 16; ++r) {
                  int prow = mi * 32 + (r & 3) + 8 * (r >> 2) + 4 * (lane >> 5);
                  float v = relu(acc[mi][ni][r]);
                  bf16_t h = (bf16_t)v;
                  sTh[prow][ncol] = h;
                  sTl[prow][ncol] = (bf16_t)(v - (float)h);
                }
            }
          }
        }
        __syncthreads();
        size_t obase = ((size_t)(blockIdx.x * RB + rge) * KOc + (blockIdx.y * NCC + cc)) * 8192;
#pragma unroll
        for (int it = 0; it < 4; ++it) {
          int f = tid + it * 256;        // vec8 index in [0,1024)
          int s = f >> 8, mi = (f >> 6) & 3, ln = f & 63;
          int rr = mi * 32 + (ln & 31), kk = s * 16 + (ln >> 5) * 8;
          *(bf16x8*)(Oh + obase + (size_t)f * 8) = *(const bf16x8*)&sTh[rr][kk];
          *(bf16x8*)(Ol + obase + (size_t)f * 8) = *(const bf16x8*)&sTl[rr][kk];
        }
        __syncthreads();
      }
  } else if constexpr (MODE == 1) {
#pragma unroll
    for (int ni = 0; ni < NI; ++ni) {
      float m = 0.f;
#pragma unroll
      for (int mi = 0; mi < 4; ++mi)
#pragma unroll
        for (int r = 0; r < 16; ++r) m = fmaxf(m, relu(acc[mi][ni][r]));
      m = fmaxf(m, __shfl_xor(m, 32));
      if (lane < 32) aux[(size_t)blockIdx.x * 1024 + (st0 + ni) * 32 + lane] = m;
    }
  } else {
    __shared__ float sp2[4][128];
    float w8v = w8[st0 * 32 + (lane & 31)];
#pragma unroll
    for (int mi = 0; mi < 4; ++mi)
#pragma unroll
      for (int r = 0; r < 16; ++r) {
        float v = relu(acc[mi][0][r]) * w8v;
        v += __shfl_xor(v, 1);
        v += __shfl_xor(v, 2);
        v += __shfl_xor(v, 4);
        v += __shfl_xor(v, 8);
        v += __shfl_xor(v, 16);
        if ((lane & 31) == 0)
          sp2[w][mi * 32 + (r & 3) + 8 * (r >> 2) + 4 * (lane >> 5)] = v;
      }
    __syncthreads();
    if (tid < 128)
      aux[(size_t)blockIdx.x * 128 + tid] =
          sp2[0][tid] + sp2[1][tid] + sp2[2][tid] + sp2[3][tid] + b8[0];
  }
}

// ============ kgmax: g[c] = max over 512 rows of gpart[512][1024]
__global__ __launch_bounds__(256) void kgmax(const float* __restrict__ gpart, float* __restrict__ g) {
  int t = blockIdx.x * 256 + threadIdx.x;  // 8192 threads
  int c = t & 1023, rg = t >> 10;
  const float* gp = gpart + (size_t)rg * 64 * 1024 + c;
  float m = 0.f;
#pragma unroll 8
  for (int r = 0; r < 64; ++r) m = fmaxf(m, gp[(size_t)r * 1024]);
  atomicMax((unsigned int*)(g + c), __float_as_uint(m));  // all values >= 0
}

// ============ kc5: c5[c] = W5[c][64:1088] @ g + b5[c]   (fp32)
__global__ __launch_bounds__(256) void kc5(
    const float* __restrict__ W5, const float* __restrict__ b5,
    const float* __restrict__ g, float* __restrict__ c5) {
  int tid = threadIdx.x;
  int ci = tid >> 3, kg = tid & 7;
  int c = blockIdx.x * 32 + ci;
  const float* wrow = W5 + (size_t)c * 1088 + 64 + kg * 128;
  const float* gp = g + kg * 128;
  float acc = 0.f;
#pragma unroll 8
  for (int k = 0; k < 128; ++k) acc += wrow[k] * gp[k];
#pragma unroll
  for (int off = 1; off <= 4; off <<= 1) acc += __shfl_xor(acc, off);
  if (kg == 0) c5[c] = acc + b5[c];
}

extern "C" void kernel_launch(void* const* d_in, const int* in_sizes, int n_in,
                              void* d_out, int out_size, void* d_ws, size_t ws_size,
                              hipStream_t stream) {
  const float* x  = (const float*)d_in[0];
  const float* W1 = (const float*)d_in[1];  const float* b1 = (const float*)d_in[2];
  const float* W2 = (const float*)d_in[3];  const float* b2 = (const float*)d_in[4];
  const float* W3 = (const float*)d_in[5];  const float* b3 = (const float*)d_in[6];
  const float* W4 = (const float*)d_in[7];  const float* b4 = (const float*)d_in[8];
  const float* W5 = (const float*)d_in[9];  const float* b5 = (const float*)d_in[10];
  const float* W6 = (const float*)d_in[11]; const float* b6 = (const float*)d_in[12];
  const float* W7 = (const float*)d_in[13]; const float* b7 = (const float*)d_in[14];
  const float* W8 = (const float*)d_in[15]; const float* b8 = (const float*)d_in[16];
  float* out = (float*)d_out;

  // Workspace overlays (MB offsets; lifetimes):
  //   z5 pair [0,128)    L5->L6
  //   h2 pair [128,144)  L2->L5
  //   h1 pair [144,160)  k1a->L2
  //   y3 pair [144,176)  L3->L4  (over dead h1)
  //   z6 pair [144,208)  L6->L7  (over dead y3)
  //   gpart [208,210), g/c5/weight-frags [210,~212)
  const size_t MB = 1ull << 20;
  char* ws = (char*)d_ws;
  bf16_t* z5h = (bf16_t*)(ws);             bf16_t* z5l = (bf16_t*)(ws + 64 * MB);
  bf16_t* h2h = (bf16_t*)(ws + 128 * MB);  bf16_t* h2l = (bf16_t*)(ws + 136 * MB);
  bf16_t* h1h = (bf16_t*)(ws + 144 * MB);  bf16_t* h1l = (bf16_t*)(ws + 152 * MB);
  bf16_t* y3h = (bf16_t*)(ws + 144 * MB);  bf16_t* y3l = (bf16_t*)(ws + 160 * MB);
  bf16_t* z6h = (bf16_t*)(ws + 144 * MB);  bf16_t* z6l = (bf16_t*)(ws + 176 * MB);
  float* gpart = (float*)(ws + 208 * MB);
  float* g     = (float*)(ws + 210 * MB);
  float* c5    = (float*)(ws + 210 * MB + 4096);
  char* wb = ws + 210 * MB + 65536;
  bf16_t* W2h = (bf16_t*)(wb);             bf16_t* W2l = (bf16_t*)(wb + 8192);
  bf16_t* W3h = (bf16_t*)(wb + 16384);     bf16_t* W3l = (bf16_t*)(wb + 32768);
  bf16_t* W4h = (bf16_t*)(wb + 49152);     bf16_t* W4l = (bf16_t*)(wb + 311296);
  bf16_t* W5h = (bf16_t*)(wb + 573440);    bf16_t* W5l = (bf16_t*)(wb + 638976);
  bf16_t* W6h = (bf16_t*)(wb + 704512);    bf16_t* W6l = (bf16_t*)(wb + 966656);
  bf16_t* W7h = (bf16_t*)(wb + 1228800);   bf16_t* W7l = (bf16_t*)(wb + 1294336);

  hipMemsetAsync(g, 0, 1024 * sizeof(float), stream);  // max identity (relu outputs >= 0)

  PrepAll pa;
  pa.seg[0] = {W2, W2h, W2l, 64, 64, 2};
  pa.seg[1] = {W3, W3h, W3l, 64, 64, 4};
  pa.seg[2] = {W4, W4h, W4l, 128, 128, 64};
  pa.seg[3] = {W5, W5h, W5l, 1088, 64, 16};   // W5[:, :64]
  pa.seg[4] = {W6, W6h, W6l, 512, 512, 64};
  pa.seg[5] = {W7, W7h, W7l, 256, 256, 16};
  kprep<<<166, 256, 0, stream>>>(pa);

  k1a<<<256, 256, 0, stream>>>(x, W1, b1, h1h, h1l);
  gemmF<2, 1, 64, 0><<<dim3(256, 1), 256, 0, stream>>>(
      h1h, h1l, W2h, W2l, b2, h2h, h2l, nullptr, nullptr, nullptr);            // L2
  gemmF<1, 1, 64, 0><<<dim3(512, 1), 256, 0, stream>>>(
      h2h, h2l, W3h, W3l, b3, y3h, y3l, nullptr, nullptr, nullptr);            // L3
  gemmF<1, 2, 128, 1><<<dim3(512, 4), 256, 0, stream>>>(
      y3h, y3l, W4h, W4l, b4, nullptr, nullptr, gpart, nullptr, nullptr);      // L4 + max
  kgmax<<<32, 256, 0, stream>>>(gpart, g);
  kc5<<<16, 256, 0, stream>>>(W5, b5, g, c5);
  gemmF<1, 2, 64, 0><<<dim3(512, 2), 256, 0, stream>>>(
      h2h, h2l, W5h, W5l, c5, z5h, z5l, nullptr, nullptr, nullptr);            // L5
  gemmF<1, 2, 512, 0><<<dim3(512, 1), 256, 0, stream>>>(
      z5h, z5l, W6h, W6l, b6, z6h, z6l, nullptr, nullptr, nullptr);            // L6
  gemmF<1, 1, 256, 2><<<dim3(512, 1), 256, 0, stream>>>(
      z6h, z6l, W7h, W7l, b7, nullptr, nullptr, out, W8, b8);                  // L7 + L8
}

// Round 7
// 338.431 us; speedup vs baseline: 1.2155x; 1.2155x over previous
//
#include <hip/hip_runtime.h>

#define NPTS 65536

typedef __bf16 bf16_t;
typedef __bf16 bf16x8 __attribute__((ext_vector_type(8)));
typedef float f32x16 __attribute__((ext_vector_type(16)));

__device__ __forceinline__ float relu(float v) { return v > 0.f ? v : 0.f; }

// Layout contracts (vec8 index; j in [0,8)):
// Activation (C ch):  idx = ((b*(C/16)+kc)*4+mi)*64 + l
//   point = b*128 + mi*32 + (l&31); channel = kc*16 + (l>>5)*8 + j
// Weight (N x K):     idx = (st*(K/16)+kc)*64 + l
//   n = st*32 + (l&31); k = kc*16 + (l>>5)*8 + j

// ============ kprep: pack fp32 weights into hi/lo bf16 A-fragment order
struct PrepSeg { const float* src; bf16_t* h; bf16_t* l; int SW; int K; int nblk; };
struct PrepAll { PrepSeg seg[6]; };

__global__ __launch_bounds__(256) void kprep(PrepAll pa) {
  int blk = blockIdx.x, i = 0;
  while (blk >= pa.seg[i].nblk) { blk -= pa.seg[i].nblk; ++i; }
  const PrepSeg sg = pa.seg[i];
  int t8 = blk * 256 + threadIdx.x;
  int l = t8 & 63;
  int rest = t8 >> 6;
  int NKC = sg.K >> 4;
  int kc = rest % NKC, st = rest / NKC;
  int n = st * 32 + (l & 31);
  int k0 = kc * 16 + (l >> 5) * 8;
  const float* src = sg.src + (size_t)n * sg.SW + k0;
  bf16x8 hv, lv;
#pragma unroll
  for (int j = 0; j < 8; ++j) {
    float v = src[j];
    bf16_t h = (bf16_t)v;
    hv[j] = h; lv[j] = (bf16_t)(v - (float)h);
  }
  *(bf16x8*)(sg.h + (size_t)t8 * 8) = hv;
  *(bf16x8*)(sg.l + (size_t)t8 * 8) = lv;
}

// ============ k1a: h1 = relu(x@W1.T+b1), written in activation (B-frag) order
__global__ __launch_bounds__(256, 2) void k1a(
    const float* __restrict__ x, const float* __restrict__ W1, const float* __restrict__ b1,
    bf16_t* __restrict__ h1h, bf16_t* __restrict__ h1l) {
  int p = blockIdx.x * 256 + threadIdx.x;
  float x0 = x[p * 3 + 0], x1 = x[p * 3 + 1], x2 = x[p * 3 + 2];
  int b = p >> 7, mi = (p >> 5) & 3, p31 = p & 31;
#pragma unroll
  for (int kc = 0; kc < 4; ++kc)
#pragma unroll
    for (int hbw = 0; hbw < 2; ++hbw) {
      bf16x8 hv, lv;
#pragma unroll
      for (int j = 0; j < 8; ++j) {
        int c = kc * 16 + hbw * 8 + j;
        float v = relu(fmaf(W1[c * 3], x0, fmaf(W1[c * 3 + 1], x1, fmaf(W1[c * 3 + 2], x2, b1[c]))));
        bf16_t h = (bf16_t)v;
        hv[j] = h; lv[j] = (bf16_t)(v - (float)h);
      }
      size_t off = (((size_t)(b * 4 + kc) * 4 + mi) * 64 + hbw * 32 + p31) * 8;
      *(bf16x8*)(h1h + off) = hv;
      *(bf16x8*)(h1l + off) = lv;
    }
}

// ============ gemmS: D = W·X^T (channels-major), 3-term split 32x32x16 bf16 MFMA.
// Weights = A-operand (global->reg, frag-packed); activations = B-operand (LDS, contiguous).
// PB point-blocks of 128; WC=4/PB channel wave-groups x NI strips of 32 ch.
// MODE 0: direct register epilogue (shfl_xor(32) channel regroup) -> activation-order store.
// MODE 1: fused point-max -> aux[bx*1024+ch]. MODE 2: fused dot with w8 -> aux[point].
template <int PB, int NI, int K, int MODE>
__global__ __launch_bounds__(256, 2) void gemmS(
    const bf16_t* __restrict__ Ah, const bf16_t* __restrict__ Al,
    const bf16_t* __restrict__ Wh, const bf16_t* __restrict__ Wl,
    const float* __restrict__ bias, int nko,
    bf16_t* __restrict__ Oh, bf16_t* __restrict__ Ol,
    float* __restrict__ aux, const float* __restrict__ w8, const float* __restrict__ b8) {
  constexpr int WC = 4 / PB;
  constexpr int NKC = K / 16;
  constexpr int KG = 4;
  constexpr int NG = NKC / KG;
  constexpr int DB = (NG > 1) ? 2 : 1;
  __shared__ char smem[DB * PB * 32768];
  __shared__ float sp[4][128];

  int tid = threadIdx.x;
  int lane = tid & 63;
  int w = __builtin_amdgcn_readfirstlane(tid >> 6);
  int rg = w / WC, cw = w % WC;
  int hb = lane >> 5, p31 = lane & 31;
  int bx = blockIdx.x;
  int st0 = blockIdx.y * (WC * NI) + cw * NI;
  int bblk = bx * PB + rg;

  f32x16 acc[4][NI];
#pragma unroll
  for (int ni = 0; ni < NI; ++ni)
#pragma unroll
    for (int r = 0; r < 16; ++r) {
      float bv = bias[(st0 + ni) * 32 + 8 * (r >> 2) + 4 * hb + (r & 3)];
#pragma unroll
      for (int mi = 0; mi < 4; ++mi) acc[mi][ni][r] = bv;
    }

  auto stage = [&](int buf, int g) {
#pragma unroll
    for (int i = 0; i < PB * 8; ++i) {
      int u = i * 256 + tid;
      int rgs = u >> 11;
      int t = (u >> 10) & 1;
      int unit = u & 1023;
      const bf16_t* src = (t ? Al : Ah) +
          ((size_t)((bx * PB + rgs) * NKC + g * KG)) * 2048 + unit * 8;
      char* dst = smem + (size_t)(((buf * PB + rgs) * 2 + t)) * 16384 + unit * 16;
      *(bf16x8*)dst = *(const bf16x8*)src;
    }
  };

  auto compute = [&](int buf, int g) {
    const char* bhp = smem + (size_t)((buf * PB + rg) * 2 + 0) * 16384;
    const char* blp = smem + (size_t)((buf * PB + rg) * 2 + 1) * 16384;
#pragma unroll
    for (int kcl = 0; kcl < KG; ++kcl) {
      int kc = g * KG + kcl;
      bf16x8 awh[NI], awl[NI];
#pragma unroll
      for (int ni = 0; ni < NI; ++ni) {
        size_t wo = ((size_t)((st0 + ni) * NKC + kc) * 64 + lane) * 8;
        awh[ni] = *(const bf16x8*)(Wh + wo);
        awl[ni] = *(const bf16x8*)(Wl + wo);
      }
#pragma unroll
      for (int mi = 0; mi < 4; ++mi) {
        int off = ((kcl * 4 + mi) * 64 + lane) * 16;
        bf16x8 xh = *(const bf16x8*)(bhp + off);
        bf16x8 xl = *(const bf16x8*)(blp + off);
#pragma unroll
        for (int ni = 0; ni < NI; ++ni) {
          acc[mi][ni] = __builtin_amdgcn_mfma_f32_32x32x16_bf16(awh[ni], xh, acc[mi][ni], 0, 0, 0);
          acc[mi][ni] = __builtin_amdgcn_mfma_f32_32x32x16_bf16(awl[ni], xh, acc[mi][ni], 0, 0, 0);
          acc[mi][ni] = __builtin_amdgcn_mfma_f32_32x32x16_bf16(awh[ni], xl, acc[mi][ni], 0, 0, 0);
        }
      }
    }
  };

  stage(0, 0);
  for (int g = 0; g < NG; ++g) {
    __syncthreads();
    if (g + 1 < NG) stage((g + 1) % DB, g + 1);
    compute(g % DB, g);
  }

  if constexpr (MODE == 0) {
    // D rows = channels, cols = points. Lane l holds 4-ch runs {8q+4hb..+3}; partner
    // l^32 (same points) holds the complementary runs -> one shfl_xor(32) assembles
    // consumer 8-ch octets. hb=0 -> kc_out=2st (octets 0,1); hb=1 -> 2st+1 (octets 2,3).
#pragma unroll
    for (int mi = 0; mi < 4; ++mi)
#pragma unroll
      for (int ni = 0; ni < NI; ++ni) {
        float a[16], rcv[8];
#pragma unroll
        for (int r = 0; r < 16; ++r) a[r] = relu(acc[mi][ni][r]);
#pragma unroll
        for (int j = 0; j < 8; ++j) rcv[j] = __shfl_xor(hb ? a[j] : a[8 + j], 32);
        float o0[8], o1[8];
#pragma unroll
        for (int j = 0; j < 4; ++j) {
          o0[j]     = hb ? rcv[j]     : a[j];
          o0[4 + j] = hb ? a[8 + j]   : rcv[j];
          o1[j]     = hb ? rcv[4 + j] : a[4 + j];
          o1[4 + j] = hb ? a[12 + j]  : rcv[4 + j];
        }
        bf16x8 h0, l0, h1, l1;
#pragma unroll
        for (int j = 0; j < 8; ++j) {
          bf16_t x0 = (bf16_t)o0[j]; h0[j] = x0; l0[j] = (bf16_t)(o0[j] - (float)x0);
          bf16_t x1 = (bf16_t)o1[j]; h1[j] = x1; l1[j] = (bf16_t)(o1[j] - (float)x1);
        }
        int kco = (st0 + ni) * 2 + hb;
        size_t ob = ((size_t)(bblk * nko + kco) * 4 + mi) * 64;
        *(bf16x8*)(Oh + (ob + p31) * 8)      = h0;
        *(bf16x8*)(Ol + (ob + p31) * 8)      = l0;
        *(bf16x8*)(Oh + (ob + 32 + p31) * 8) = h1;
        *(bf16x8*)(Ol + (ob + 32 + p31) * 8) = l1;
      }
  } else if constexpr (MODE == 1) {
#pragma unroll
    for (int ni = 0; ni < NI; ++ni)
#pragma unroll
      for (int r = 0; r < 16; ++r) {
        float m = relu(acc[0][ni][r]);
#pragma unroll
        for (int mi = 1; mi < 4; ++mi) m = fmaxf(m, relu(acc[mi][ni][r]));
#pragma unroll
        for (int off = 1; off < 32; off <<= 1) m = fmaxf(m, __shfl_xor(m, off));
        if (p31 == 0)
          aux[(size_t)bx * 1024 + (st0 + ni) * 32 + 8 * (r >> 2) + 4 * hb + (r & 3)] = m;
      }
  } else {
    float w8v[16];
#pragma unroll
    for (int r = 0; r < 16; ++r) w8v[r] = w8[st0 * 32 + 8 * (r >> 2) + 4 * hb + (r & 3)];
#pragma unroll
    for (int mi = 0; mi < 4; ++mi) {
      float s = 0.f;
#pragma unroll
      for (int r = 0; r < 16; ++r) s = fmaf(relu(acc[mi][0][r]), w8v[r], s);
      s += __shfl_xor(s, 32);
      if (hb == 0) sp[w][mi * 32 + p31] = s;
    }
    __syncthreads();
    if (tid < 128)
      aux[(size_t)bx * 128 + tid] = sp[0][tid] + sp[1][tid] + sp[2][tid] + sp[3][tid] + b8[0];
  }
}

// ============ kgmax: g[c] = max over 512 rows of gpart[512][1024]
__global__ __launch_bounds__(256) void kgmax(const float* __restrict__ gpart, float* __restrict__ g) {
  int t = blockIdx.x * 256 + threadIdx.x;  // 8192 threads
  int c = t & 1023, rg = t >> 10;
  const float* gp = gpart + (size_t)rg * 64 * 1024 + c;
  float m = 0.f;
#pragma unroll 8
  for (int r = 0; r < 64; ++r) m = fmaxf(m, gp[(size_t)r * 1024]);
  atomicMax((unsigned int*)(g + c), __float_as_uint(m));  // all values >= 0
}

// ============ kc5: c5[c] = W5[c][64:1088] @ g + b5[c]   (fp32)
__global__ __launch_bounds__(256) void kc5(
    const float* __restrict__ W5, const float* __restrict__ b5,
    const float* __restrict__ g, float* __restrict__ c5) {
  int tid = threadIdx.x;
  int ci = tid >> 3, kg = tid & 7;
  int c = blockIdx.x * 32 + ci;
  const float* wrow = W5 + (size_t)c * 1088 + 64 + kg * 128;
  const float* gp = g + kg * 128;
  float acc = 0.f;
#pragma unroll 8
  for (int k = 0; k < 128; ++k) acc += wrow[k] * gp[k];
#pragma unroll
  for (int off = 1; off <= 4; off <<= 1) acc += __shfl_xor(acc, off);
  if (kg == 0) c5[c] = acc + b5[c];
}

extern "C" void kernel_launch(void* const* d_in, const int* in_sizes, int n_in,
                              void* d_out, int out_size, void* d_ws, size_t ws_size,
                              hipStream_t stream) {
  const float* x  = (const float*)d_in[0];
  const float* W1 = (const float*)d_in[1];  const float* b1 = (const float*)d_in[2];
  const float* W2 = (const float*)d_in[3];  const float* b2 = (const float*)d_in[4];
  const float* W3 = (const float*)d_in[5];  const float* b3 = (const float*)d_in[6];
  const float* W4 = (const float*)d_in[7];  const float* b4 = (const float*)d_in[8];
  const float* W5 = (const float*)d_in[9];  const float* b5 = (const float*)d_in[10];
  const float* W6 = (const float*)d_in[11]; const float* b6 = (const float*)d_in[12];
  const float* W7 = (const float*)d_in[13]; const float* b7 = (const float*)d_in[14];
  const float* W8 = (const float*)d_in[15]; const float* b8 = (const float*)d_in[16];
  float* out = (float*)d_out;

  // Workspace overlays (MB offsets; lifetimes):
  //   z5 pair [0,64)+[64,128)  L5->L6
  //   h2 pair [128,136)+[136,144)  L2->L5
  //   h1 pair [144,152)+[152,160)  k1a->L2
  //   y3 pair [144,160)+[160,176)  L3->L4  (over dead h1)
  //   z6 pair [144,176)+[176,208)  L6->L7  (over dead y3)
  //   gpart [208,210), g/c5 [210,..), weight frags after
  const size_t MB = 1ull << 20;
  char* ws = (char*)d_ws;
  bf16_t* z5h = (bf16_t*)(ws);             bf16_t* z5l = (bf16_t*)(ws + 64 * MB);
  bf16_t* h2h = (bf16_t*)(ws + 128 * MB);  bf16_t* h2l = (bf16_t*)(ws + 136 * MB);
  bf16_t* h1h = (bf16_t*)(ws + 144 * MB);  bf16_t* h1l = (bf16_t*)(ws + 152 * MB);
  bf16_t* y3h = (bf16_t*)(ws + 144 * MB);  bf16_t* y3l = (bf16_t*)(ws + 160 * MB);
  bf16_t* z6h = (bf16_t*)(ws + 144 * MB);  bf16_t* z6l = (bf16_t*)(ws + 176 * MB);
  float* gpart = (float*)(ws + 208 * MB);
  float* g     = (float*)(ws + 210 * MB);
  float* c5    = (float*)(ws + 210 * MB + 4096);
  char* wb = ws + 210 * MB + 65536;
  bf16_t* W2h = (bf16_t*)(wb);             bf16_t* W2l = (bf16_t*)(wb + 8192);
  bf16_t* W3h = (bf16_t*)(wb + 16384);     bf16_t* W3l = (bf16_t*)(wb + 32768);
  bf16_t* W4h = (bf16_t*)(wb + 49152);     bf16_t* W4l = (bf16_t*)(wb + 311296);
  bf16_t* W5h = (bf16_t*)(wb + 573440);    bf16_t* W5l = (bf16_t*)(wb + 638976);
  bf16_t* W6h = (bf16_t*)(wb + 704512);    bf16_t* W6l = (bf16_t*)(wb + 966656);
  bf16_t* W7h = (bf16_t*)(wb + 1228800);   bf16_t* W7l = (bf16_t*)(wb + 1294336);

  hipMemsetAsync(g, 0, 1024 * sizeof(float), stream);  // max identity (relu outputs >= 0)

  PrepAll pa;
  pa.seg[0] = {W2, W2h, W2l, 64, 64, 2};
  pa.seg[1] = {W3, W3h, W3l, 64, 64, 4};
  pa.seg[2] = {W4, W4h, W4l, 128, 128, 64};
  pa.seg[3] = {W5, W5h, W5l, 1088, 64, 16};   // W5[:, :64]
  pa.seg[4] = {W6, W6h, W6l, 512, 512, 64};
  pa.seg[5] = {W7, W7h, W7l, 256, 256, 16};
  kprep<<<166, 256, 0, stream>>>(pa);

  k1a<<<256, 256, 0, stream>>>(x, W1, b1, h1h, h1l);
  gemmS<2, 1, 64, 0><<<dim3(256, 1), 256, 0, stream>>>(
      h1h, h1l, W2h, W2l, b2, 4, h2h, h2l, nullptr, nullptr, nullptr);        // L2
  gemmS<1, 1, 64, 0><<<dim3(512, 1), 256, 0, stream>>>(
      h2h, h2l, W3h, W3l, b3, 8, y3h, y3l, nullptr, nullptr, nullptr);        // L3
  gemmS<1, 2, 128, 1><<<dim3(512, 4), 256, 0, stream>>>(
      y3h, y3l, W4h, W4l, b4, 0, nullptr, nullptr, gpart, nullptr, nullptr);  // L4 + max
  kgmax<<<32, 256, 0, stream>>>(gpart, g);
  kc5<<<16, 256, 0, stream>>>(W5, b5, g, c5);
  gemmS<1, 2, 64, 0><<<dim3(512, 2), 256, 0, stream>>>(
      h2h, h2l, W5h, W5l, c5, 32, z5h, z5l, nullptr, nullptr, nullptr);       // L5
  gemmS<1, 2, 512, 0><<<dim3(512, 1), 256, 0, stream>>>(
      z5h, z5l, W6h, W6l, b6, 16, z6h, z6l, nullptr, nullptr, nullptr);       // L6
  gemmS<1, 1, 256, 2><<<dim3(512, 1), 256, 0, stream>>>(
      z6h, z6l, W7h, W7l, b7, 0, nullptr, nullptr, out, W8, b8);              // L7 + L8
}

// Round 8
// 330.499 us; speedup vs baseline: 1.2446x; 1.0240x over previous
//
#include <hip/hip_runtime.h>

#define NPTS 65536

typedef __bf16 bf16_t;
typedef __bf16 bf16x8 __attribute__((ext_vector_type(8)));
typedef float f32x16 __attribute__((ext_vector_type(16)));

__device__ __forceinline__ float relu(float v) { return v > 0.f ? v : 0.f; }

// Layout contracts (vec8 index; j in [0,8)):
// Activation (C ch):  idx = ((b*(C/16)+kc)*4+mi)*64 + l
//   point = b*128 + mi*32 + (l&31); channel = kc*16 + (l>>5)*8 + j
// Weight (N x K):     idx = (st*(K/16)+kc)*64 + l
//   n = st*32 + (l&31); k = kc*16 + (l>>5)*8 + j

// ============ kprep: pack fp32 weights into hi/lo bf16 A-fragment order
struct PrepSeg { const float* src; bf16_t* h; bf16_t* l; int SW; int K; int nblk; };
struct PrepAll { PrepSeg seg[6]; };

__global__ __launch_bounds__(256) void kprep(PrepAll pa) {
  int blk = blockIdx.x, i = 0;
  while (blk >= pa.seg[i].nblk) { blk -= pa.seg[i].nblk; ++i; }
  const PrepSeg sg = pa.seg[i];
  int t8 = blk * 256 + threadIdx.x;
  int l = t8 & 63;
  int rest = t8 >> 6;
  int NKC = sg.K >> 4;
  int kc = rest % NKC, st = rest / NKC;
  int n = st * 32 + (l & 31);
  int k0 = kc * 16 + (l >> 5) * 8;
  const float* src = sg.src + (size_t)n * sg.SW + k0;
  bf16x8 hv, lv;
#pragma unroll
  for (int j = 0; j < 8; ++j) {
    float v = src[j];
    bf16_t h = (bf16_t)v;
    hv[j] = h; lv[j] = (bf16_t)(v - (float)h);
  }
  *(bf16x8*)(sg.h + (size_t)t8 * 8) = hv;
  *(bf16x8*)(sg.l + (size_t)t8 * 8) = lv;
}

// ============ k1a: h1 = relu(x@W1.T+b1), written in activation (B-frag) order
__global__ __launch_bounds__(256, 2) void k1a(
    const float* __restrict__ x, const float* __restrict__ W1, const float* __restrict__ b1,
    bf16_t* __restrict__ h1h, bf16_t* __restrict__ h1l) {
  int p = blockIdx.x * 256 + threadIdx.x;
  float x0 = x[p * 3 + 0], x1 = x[p * 3 + 1], x2 = x[p * 3 + 2];
  int b = p >> 7, mi = (p >> 5) & 3, p31 = p & 31;
#pragma unroll
  for (int kc = 0; kc < 4; ++kc)
#pragma unroll
    for (int hbw = 0; hbw < 2; ++hbw) {
      bf16x8 hv, lv;
#pragma unroll
      for (int j = 0; j < 8; ++j) {
        int c = kc * 16 + hbw * 8 + j;
        float v = relu(fmaf(W1[c * 3], x0, fmaf(W1[c * 3 + 1], x1, fmaf(W1[c * 3 + 2], x2, b1[c]))));
        bf16_t h = (bf16_t)v;
        hv[j] = h; lv[j] = (bf16_t)(v - (float)h);
      }
      size_t off = (((size_t)(b * 4 + kc) * 4 + mi) * 64 + hbw * 32 + p31) * 8;
      *(bf16x8*)(h1h + off) = hv;
      *(bf16x8*)(h1l + off) = lv;
    }
}

// ============ gemmS: D = W·X^T, 3-term split 32x32x16 bf16 MFMA.
// Wave owns one 32-ch strip x 128 pts (acc = 64 VGPRs). Weights double-prefetched
// global->reg; activations double-buffered LDS (contiguous frag-major copy).
// MODE 0: register epilogue (shfl_xor(32)) -> activation-order store.
// MODE 1: fused point-max -> aux[bx*1024+ch]. MODE 2: fused dot with w8 -> aux[point].
template <int PB, int K, int MODE>
__global__ __launch_bounds__(256, 3) void gemmS(
    const bf16_t* __restrict__ Ah, const bf16_t* __restrict__ Al,
    const bf16_t* __restrict__ Wh, const bf16_t* __restrict__ Wl,
    const float* __restrict__ bias, int nko,
    bf16_t* __restrict__ Oh, bf16_t* __restrict__ Ol,
    float* __restrict__ aux, const float* __restrict__ w8, const float* __restrict__ b8) {
  constexpr int WC = 4 / PB;
  constexpr int NKC = K / 16;
  constexpr int KG = 2;              // 2 kc (32 k) per LDS chunk -> 16 KB per buffer
  constexpr int NG = NKC / KG;
  __shared__ bf16_t smem[2][PB][2][KG * 2048];

  int tid = threadIdx.x;
  int lane = tid & 63;
  int w = __builtin_amdgcn_readfirstlane(tid >> 6);
  int rg = w / WC, cw = w % WC;
  int hb = lane >> 5, p31 = lane & 31;
  int bx = blockIdx.x;
  int st0 = blockIdx.y * WC + cw;
  int bblk = bx * PB + rg;

  f32x16 acc[4];
#pragma unroll
  for (int r = 0; r < 16; ++r) {
    float bv = bias[st0 * 32 + 8 * (r >> 2) + 4 * hb + (r & 3)];
#pragma unroll
    for (int mi = 0; mi < 4; ++mi) acc[mi][r] = bv;
  }

  auto stage = [&](int buf, int g) {
#pragma unroll
    for (int i = 0; i < PB * 4; ++i) {
      int u = i * 256 + tid;
      int rgs = u >> 10, rem = u & 1023;
      int t = rem >> 9, inner = rem & 511;
      const bf16_t* src = (t ? Al : Ah) +
          ((size_t)(bx * PB + rgs) * NKC + g * KG) * 2048 + inner * 8;
      *(bf16x8*)&smem[buf][rgs][t][inner * 8] = *(const bf16x8*)src;
    }
  };

  bf16x8 wch[KG], wcl[KG], wnh[KG], wnl[KG];
  auto wload = [&](int g, bf16x8* h, bf16x8* l) {
#pragma unroll
    for (int kcl = 0; kcl < KG; ++kcl) {
      size_t wo = (((size_t)st0 * NKC + g * KG + kcl) * 64 + lane) * 8;
      h[kcl] = *(const bf16x8*)(Wh + wo);
      l[kcl] = *(const bf16x8*)(Wl + wo);
    }
  };

  auto compute = [&](int buf, bf16x8* h, bf16x8* l) {
#pragma unroll
    for (int kcl = 0; kcl < KG; ++kcl)
#pragma unroll
      for (int mi = 0; mi < 4; ++mi) {
        const bf16_t* xp = &smem[buf][rg][0][((kcl * 4 + mi) * 64 + lane) * 8];
        bf16x8 xh = *(const bf16x8*)xp;
        bf16x8 xl = *(const bf16x8*)(xp + KG * 2048);
        acc[mi] = __builtin_amdgcn_mfma_f32_32x32x16_bf16(h[kcl], xh, acc[mi], 0, 0, 0);
        acc[mi] = __builtin_amdgcn_mfma_f32_32x32x16_bf16(l[kcl], xh, acc[mi], 0, 0, 0);
        acc[mi] = __builtin_amdgcn_mfma_f32_32x32x16_bf16(h[kcl], xl, acc[mi], 0, 0, 0);
      }
  };

  stage(0, 0);
  wload(0, wch, wcl);
  for (int g = 0; g < NG; ++g) {
    __syncthreads();
    if (g + 1 < NG) {
      stage((g + 1) & 1, g + 1);
      wload(g + 1, wnh, wnl);
    }
    compute(g & 1, wch, wcl);
#pragma unroll
    for (int kcl = 0; kcl < KG; ++kcl) { wch[kcl] = wnh[kcl]; wcl[kcl] = wnl[kcl]; }
  }

  if constexpr (MODE == 0) {
    // Lane l holds 4-ch runs; partner l^32 (same points) holds complementary runs;
    // one shfl_xor(32) assembles consumer 8-ch octets. hb selects kc_out = 2*st0+hb.
#pragma unroll
    for (int mi = 0; mi < 4; ++mi) {
      float a[16], rcv[8];
#pragma unroll
      for (int r = 0; r < 16; ++r) a[r] = relu(acc[mi][r]);
#pragma unroll
      for (int j = 0; j < 8; ++j) rcv[j] = __shfl_xor(hb ? a[j] : a[8 + j], 32);
      float o0[8], o1[8];
#pragma unroll
      for (int j = 0; j < 4; ++j) {
        o0[j]     = hb ? rcv[j]     : a[j];
        o0[4 + j] = hb ? a[8 + j]   : rcv[j];
        o1[j]     = hb ? rcv[4 + j] : a[4 + j];
        o1[4 + j] = hb ? a[12 + j]  : rcv[4 + j];
      }
      bf16x8 h0, l0, h1, l1;
#pragma unroll
      for (int j = 0; j < 8; ++j) {
        bf16_t x0 = (bf16_t)o0[j]; h0[j] = x0; l0[j] = (bf16_t)(o0[j] - (float)x0);
        bf16_t x1 = (bf16_t)o1[j]; h1[j] = x1; l1[j] = (bf16_t)(o1[j] - (float)x1);
      }
      int kco = st0 * 2 + hb;
      size_t ob = ((size_t)(bblk * nko + kco) * 4 + mi) * 64;
      *(bf16x8*)(Oh + (ob + p31) * 8)      = h0;
      *(bf16x8*)(Ol + (ob + p31) * 8)      = l0;
      *(bf16x8*)(Oh + (ob + 32 + p31) * 8) = h1;
      *(bf16x8*)(Ol + (ob + 32 + p31) * 8) = l1;
    }
  } else if constexpr (MODE == 1) {
#pragma unroll
    for (int r = 0; r < 16; ++r) {
      float m = relu(acc[0][r]);
#pragma unroll
      for (int mi = 1; mi < 4; ++mi) m = fmaxf(m, relu(acc[mi][r]));
#pragma unroll
      for (int off = 1; off < 32; off <<= 1) m = fmaxf(m, __shfl_xor(m, off));
      if (p31 == 0)
        aux[(size_t)bx * 1024 + st0 * 32 + 8 * (r >> 2) + 4 * hb + (r & 3)] = m;
    }
  } else {
    __shared__ float sp[4][128];
    float w8v[16];
#pragma unroll
    for (int r = 0; r < 16; ++r) w8v[r] = w8[st0 * 32 + 8 * (r >> 2) + 4 * hb + (r & 3)];
#pragma unroll
    for (int mi = 0; mi < 4; ++mi) {
      float s = 0.f;
#pragma unroll
      for (int r = 0; r < 16; ++r) s = fmaf(relu(acc[mi][r]), w8v[r], s);
      s += __shfl_xor(s, 32);
      if (hb == 0) sp[w][mi * 32 + p31] = s;
    }
    __syncthreads();
    if (tid < 128)
      aux[(size_t)bx * 128 + tid] = sp[0][tid] + sp[1][tid] + sp[2][tid] + sp[3][tid] + b8[0];
  }
}

// ============ kgmax: g[c] = max over 512 rows of gpart[512][1024]
__global__ __launch_bounds__(256) void kgmax(const float* __restrict__ gpart, float* __restrict__ g) {
  int t = blockIdx.x * 256 + threadIdx.x;  // 8192 threads
  int c = t & 1023, rg = t >> 10;
  const float* gp = gpart + (size_t)rg * 64 * 1024 + c;
  float m = 0.f;
#pragma unroll 8
  for (int r = 0; r < 64; ++r) m = fmaxf(m, gp[(size_t)r * 1024]);
  atomicMax((unsigned int*)(g + c), __float_as_uint(m));  // all values >= 0
}

// ============ kc5: c5[c] = W5[c][64:1088] @ g + b5[c]   (fp32)
__global__ __launch_bounds__(256) void kc5(
    const float* __restrict__ W5, const float* __restrict__ b5,
    const float* __restrict__ g, float* __restrict__ c5) {
  int tid = threadIdx.x;
  int ci = tid >> 3, kg = tid & 7;
  int c = blockIdx.x * 32 + ci;
  const float* wrow = W5 + (size_t)c * 1088 + 64 + kg * 128;
  const float* gp = g + kg * 128;
  float acc = 0.f;
#pragma unroll 8
  for (int k = 0; k < 128; ++k) acc += wrow[k] * gp[k];
#pragma unroll
  for (int off = 1; off <= 4; off <<= 1) acc += __shfl_xor(acc, off);
  if (kg == 0) c5[c] = acc + b5[c];
}

extern "C" void kernel_launch(void* const* d_in, const int* in_sizes, int n_in,
                              void* d_out, int out_size, void* d_ws, size_t ws_size,
                              hipStream_t stream) {
  const float* x  = (const float*)d_in[0];
  const float* W1 = (const float*)d_in[1];  const float* b1 = (const float*)d_in[2];
  const float* W2 = (const float*)d_in[3];  const float* b2 = (const float*)d_in[4];
  const float* W3 = (const float*)d_in[5];  const float* b3 = (const float*)d_in[6];
  const float* W4 = (const float*)d_in[7];  const float* b4 = (const float*)d_in[8];
  const float* W5 = (const float*)d_in[9];  const float* b5 = (const float*)d_in[10];
  const float* W6 = (const float*)d_in[11]; const float* b6 = (const float*)d_in[12];
  const float* W7 = (const float*)d_in[13]; const float* b7 = (const float*)d_in[14];
  const float* W8 = (const float*)d_in[15]; const float* b8 = (const float*)d_in[16];
  float* out = (float*)d_out;

  // Workspace overlays (MB offsets; lifetimes):
  //   z5 pair [0,64)+[64,128)      L5->L6
  //   h2 pair [128,136)+[136,144)  L2->L5
  //   h1 pair [144,152)+[152,160)  k1a->L2
  //   y3 pair [144,160)+[160,176)  L3->L4  (over dead h1)
  //   z6 pair [144,176)+[176,208)  L6->L7  (over dead y3)
  //   gpart [208,210), g/c5 [210,..), weight frags after
  const size_t MB = 1ull << 20;
  char* ws = (char*)d_ws;
  bf16_t* z5h = (bf16_t*)(ws);             bf16_t* z5l = (bf16_t*)(ws + 64 * MB);
  bf16_t* h2h = (bf16_t*)(ws + 128 * MB);  bf16_t* h2l = (bf16_t*)(ws + 136 * MB);
  bf16_t* h1h = (bf16_t*)(ws + 144 * MB);  bf16_t* h1l = (bf16_t*)(ws + 152 * MB);
  bf16_t* y3h = (bf16_t*)(ws + 144 * MB);  bf16_t* y3l = (bf16_t*)(ws + 160 * MB);
  bf16_t* z6h = (bf16_t*)(ws + 144 * MB);  bf16_t* z6l = (bf16_t*)(ws + 176 * MB);
  float* gpart = (float*)(ws + 208 * MB);
  float* g     = (float*)(ws + 210 * MB);
  float* c5    = (float*)(ws + 210 * MB + 4096);
  char* wb = ws + 210 * MB + 65536;
  bf16_t* W2h = (bf16_t*)(wb);             bf16_t* W2l = (bf16_t*)(wb + 8192);
  bf16_t* W3h = (bf16_t*)(wb + 16384);     bf16_t* W3l = (bf16_t*)(wb + 32768);
  bf16_t* W4h = (bf16_t*)(wb + 49152);     bf16_t* W4l = (bf16_t*)(wb + 311296);
  bf16_t* W5h = (bf16_t*)(wb + 573440);    bf16_t* W5l = (bf16_t*)(wb + 638976);
  bf16_t* W6h = (bf16_t*)(wb + 704512);    bf16_t* W6l = (bf16_t*)(wb + 966656);
  bf16_t* W7h = (bf16_t*)(wb + 1228800);   bf16_t* W7l = (bf16_t*)(wb + 1294336);

  hipMemsetAsync(g, 0, 1024 * sizeof(float), stream);  // max identity (relu outputs >= 0)

  PrepAll pa;
  pa.seg[0] = {W2, W2h, W2l, 64, 64, 2};
  pa.seg[1] = {W3, W3h, W3l, 64, 64, 4};
  pa.seg[2] = {W4, W4h, W4l, 128, 128, 64};
  pa.seg[3] = {W5, W5h, W5l, 1088, 64, 16};   // W5[:, :64]
  pa.seg[4] = {W6, W6h, W6l, 512, 512, 64};
  pa.seg[5] = {W7, W7h, W7l, 256, 256, 16};
  kprep<<<166, 256, 0, stream>>>(pa);

  k1a<<<256, 256, 0, stream>>>(x, W1, b1, h1h, h1l);
  gemmS<2, 64, 0><<<dim3(256, 1), 256, 0, stream>>>(
      h1h, h1l, W2h, W2l, b2, 4, h2h, h2l, nullptr, nullptr, nullptr);        // L2
  gemmS<1, 64, 0><<<dim3(512, 1), 256, 0, stream>>>(
      h2h, h2l, W3h, W3l, b3, 8, y3h, y3l, nullptr, nullptr, nullptr);        // L3
  gemmS<1, 128, 1><<<dim3(512, 8), 256, 0, stream>>>(
      y3h, y3l, W4h, W4l, b4, 0, nullptr, nullptr, gpart, nullptr, nullptr);  // L4 + max
  kgmax<<<32, 256, 0, stream>>>(gpart, g);
  kc5<<<16, 256, 0, stream>>>(W5, b5, g, c5);
  gemmS<1, 64, 0><<<dim3(512, 4), 256, 0, stream>>>(
      h2h, h2l, W5h, W5l, c5, 32, z5h, z5l, nullptr, nullptr, nullptr);       // L5
  gemmS<1, 512, 0><<<dim3(512, 2), 256, 0, stream>>>(
      z5h, z5l, W6h, W6l, b6, 16, z6h, z6l, nullptr, nullptr, nullptr);       // L6
  gemmS<1, 256, 2><<<dim3(512, 1), 256, 0, stream>>>(
      z6h, z6l, W7h, W7l, b7, 0, nullptr, nullptr, out, W8, b8);              // L7 + L8
}

// Round 10
// 282.460 us; speedup vs baseline: 1.4563x; 1.1701x over previous
//
#include <hip/hip_runtime.h>

#define NPTS 65536

typedef __bf16 bf16_t;
typedef __bf16 bf16x8 __attribute__((ext_vector_type(8)));
typedef float f32x16 __attribute__((ext_vector_type(16)));

#define MFMA32(A, B, C) __builtin_amdgcn_mfma_f32_32x32x16_bf16(A, B, C, 0, 0, 0)

__device__ __forceinline__ float relu(float v) { return v > 0.f ? v : 0.f; }

// ======================================================================
// R8-verbatim front half: layouts (128-pt blocks, 4 mi slots):
// Activation (C ch): octet idx = ((b*(C/16)+kc)*4+mi)*64 + l
//   point = b*128 + mi*32 + (l&31); channel = kc*16 + (l>>5)*8 + j
// Weight (N x K): octet idx = (st*(K/16)+kc)*64 + l; n = st*32+(l&31); k = kc*16+(l>>5)*8+j
// ======================================================================

struct PrepSeg { const float* src; bf16_t* h; bf16_t* l; int SW; int K; int nblk; };
struct PrepAll { PrepSeg seg[6]; };

__global__ __launch_bounds__(256) void kprep(PrepAll pa) {
  int blk = blockIdx.x, i = 0;
  while (blk >= pa.seg[i].nblk) { blk -= pa.seg[i].nblk; ++i; }
  const PrepSeg sg = pa.seg[i];
  int t8 = blk * 256 + threadIdx.x;
  int l = t8 & 63;
  int rest = t8 >> 6;
  int NKC = sg.K >> 4;
  int kc = rest % NKC, st = rest / NKC;
  int n = st * 32 + (l & 31);
  int k0 = kc * 16 + (l >> 5) * 8;
  const float* src = sg.src + (size_t)n * sg.SW + k0;
  bf16x8 hv, lv;
#pragma unroll
  for (int j = 0; j < 8; ++j) {
    float v = src[j];
    bf16_t h = (bf16_t)v;
    hv[j] = h; lv[j] = (bf16_t)(v - (float)h);
  }
  *(bf16x8*)(sg.h + (size_t)t8 * 8) = hv;
  *(bf16x8*)(sg.l + (size_t)t8 * 8) = lv;
}

// ============ k1a (R8 verbatim): h1 = relu(x@W1.T+b1) in activation order
__global__ __launch_bounds__(256, 2) void k1a(
    const float* __restrict__ x, const float* __restrict__ W1, const float* __restrict__ b1,
    bf16_t* __restrict__ h1h, bf16_t* __restrict__ h1l) {
  int p = blockIdx.x * 256 + threadIdx.x;
  float x0 = x[p * 3 + 0], x1 = x[p * 3 + 1], x2 = x[p * 3 + 2];
  int b = p >> 7, mi = (p >> 5) & 3, p31 = p & 31;
#pragma unroll
  for (int kc = 0; kc < 4; ++kc)
#pragma unroll
    for (int hbw = 0; hbw < 2; ++hbw) {
      bf16x8 hv, lv;
#pragma unroll
      for (int j = 0; j < 8; ++j) {
        int c = kc * 16 + hbw * 8 + j;
        float v = relu(fmaf(W1[c * 3], x0, fmaf(W1[c * 3 + 1], x1, fmaf(W1[c * 3 + 2], x2, b1[c]))));
        bf16_t h = (bf16_t)v;
        hv[j] = h; lv[j] = (bf16_t)(v - (float)h);
      }
      size_t off = (((size_t)(b * 4 + kc) * 4 + mi) * 64 + hbw * 32 + p31) * 8;
      *(bf16x8*)(h1h + off) = hv;
      *(bf16x8*)(h1l + off) = lv;
    }
}

// ============ gemmS (R8 verbatim): D = W·X^T, 3-term split 32x32x16 bf16 MFMA
template <int PB, int K, int MODE>
__global__ __launch_bounds__(256, 3) void gemmS(
    const bf16_t* __restrict__ Ah, const bf16_t* __restrict__ Al,
    const bf16_t* __restrict__ Wh, const bf16_t* __restrict__ Wl,
    const float* __restrict__ bias, int nko,
    bf16_t* __restrict__ Oh, bf16_t* __restrict__ Ol,
    float* __restrict__ aux, const float* __restrict__ w8, const float* __restrict__ b8) {
  constexpr int WC = 4 / PB;
  constexpr int NKC = K / 16;
  constexpr int KG = 2;
  constexpr int NG = NKC / KG;
  __shared__ bf16_t smem[2][PB][2][KG * 2048];

  int tid = threadIdx.x;
  int lane = tid & 63;
  int w = __builtin_amdgcn_readfirstlane(tid >> 6);
  int rg = w / WC, cw = w % WC;
  int hb = lane >> 5, p31 = lane & 31;
  int bx = blockIdx.x;
  int st0 = blockIdx.y * WC + cw;
  int bblk = bx * PB + rg;

  f32x16 acc[4];
#pragma unroll
  for (int r = 0; r < 16; ++r) {
    float bv = bias[st0 * 32 + 8 * (r >> 2) + 4 * hb + (r & 3)];
#pragma unroll
    for (int mi = 0; mi < 4; ++mi) acc[mi][r] = bv;
  }

  auto stage = [&](int buf, int g) {
#pragma unroll
    for (int i = 0; i < PB * 4; ++i) {
      int u = i * 256 + tid;
      int rgs = u >> 10, rem = u & 1023;
      int t = rem >> 9, inner = rem & 511;
      const bf16_t* src = (t ? Al : Ah) +
          ((size_t)(bx * PB + rgs) * NKC + g * KG) * 2048 + inner * 8;
      *(bf16x8*)&smem[buf][rgs][t][inner * 8] = *(const bf16x8*)src;
    }
  };

  bf16x8 wch[KG], wcl[KG], wnh[KG], wnl[KG];
  auto wload = [&](int g, bf16x8* h, bf16x8* l) {
#pragma unroll
    for (int kcl = 0; kcl < KG; ++kcl) {
      size_t wo = (((size_t)st0 * NKC + g * KG + kcl) * 64 + lane) * 8;
      h[kcl] = *(const bf16x8*)(Wh + wo);
      l[kcl] = *(const bf16x8*)(Wl + wo);
    }
  };

  auto compute = [&](int buf, bf16x8* h, bf16x8* l) {
#pragma unroll
    for (int kcl = 0; kcl < KG; ++kcl)
#pragma unroll
      for (int mi = 0; mi < 4; ++mi) {
        const bf16_t* xp = &smem[buf][rg][0][((kcl * 4 + mi) * 64 + lane) * 8];
        bf16x8 xh = *(const bf16x8*)xp;
        bf16x8 xl = *(const bf16x8*)(xp + KG * 2048);
        acc[mi] = MFMA32(h[kcl], xh, acc[mi]);
        acc[mi] = MFMA32(l[kcl], xh, acc[mi]);
        acc[mi] = MFMA32(h[kcl], xl, acc[mi]);
      }
  };

  stage(0, 0);
  wload(0, wch, wcl);
  for (int g = 0; g < NG; ++g) {
    __syncthreads();
    if (g + 1 < NG) {
      stage((g + 1) & 1, g + 1);
      wload(g + 1, wnh, wnl);
    }
    compute(g & 1, wch, wcl);
#pragma unroll
    for (int kcl = 0; kcl < KG; ++kcl) { wch[kcl] = wnh[kcl]; wcl[kcl] = wnl[kcl]; }
  }

  if constexpr (MODE == 0) {
#pragma unroll
    for (int mi = 0; mi < 4; ++mi) {
      float a[16], rcv[8];
#pragma unroll
      for (int r = 0; r < 16; ++r) a[r] = relu(acc[mi][r]);
#pragma unroll
      for (int j = 0; j < 8; ++j) rcv[j] = __shfl_xor(hb ? a[j] : a[8 + j], 32);
      float o0[8], o1[8];
#pragma unroll
      for (int j = 0; j < 4; ++j) {
        o0[j]     = hb ? rcv[j]     : a[j];
        o0[4 + j] = hb ? a[8 + j]   : rcv[j];
        o1[j]     = hb ? rcv[4 + j] : a[4 + j];
        o1[4 + j] = hb ? a[12 + j]  : rcv[4 + j];
      }
      bf16x8 h0, l0, h1, l1;
#pragma unroll
      for (int j = 0; j < 8; ++j) {
        bf16_t x0 = (bf16_t)o0[j]; h0[j] = x0; l0[j] = (bf16_t)(o0[j] - (float)x0);
        bf16_t x1 = (bf16_t)o1[j]; h1[j] = x1; l1[j] = (bf16_t)(o1[j] - (float)x1);
      }
      int kco = st0 * 2 + hb;
      size_t ob = ((size_t)(bblk * nko + kco) * 4 + mi) * 64;
      *(bf16x8*)(Oh + (ob + p31) * 8)      = h0;
      *(bf16x8*)(Ol + (ob + p31) * 8)      = l0;
      *(bf16x8*)(Oh + (ob + 32 + p31) * 8) = h1;
      *(bf16x8*)(Ol + (ob + 32 + p31) * 8) = l1;
    }
  } else if constexpr (MODE == 1) {
#pragma unroll
    for (int r = 0; r < 16; ++r) {
      float m = relu(acc[0][r]);
#pragma unroll
      for (int mi = 1; mi < 4; ++mi) m = fmaxf(m, relu(acc[mi][r]));
#pragma unroll
      for (int off = 1; off < 32; off <<= 1) m = fmaxf(m, __shfl_xor(m, off));
      if (p31 == 0)
        aux[(size_t)bx * 1024 + st0 * 32 + 8 * (r >> 2) + 4 * hb + (r & 3)] = m;
    }
  } else {
    __shared__ float sp[4][128];
    float w8v[16];
#pragma unroll
    for (int r = 0; r < 16; ++r) w8v[r] = w8[st0 * 32 + 8 * (r >> 2) + 4 * hb + (r & 3)];
#pragma unroll
    for (int mi = 0; mi < 4; ++mi) {
      float s = 0.f;
#pragma unroll
      for (int r = 0; r < 16; ++r) s = fmaf(relu(acc[mi][r]), w8v[r], s);
      s += __shfl_xor(s, 32);
      if (hb == 0) sp[w][mi * 32 + p31] = s;
    }
    __syncthreads();
    if (tid < 128)
      aux[(size_t)bx * 128 + tid] = sp[0][tid] + sp[1][tid] + sp[2][tid] + sp[3][tid] + b8[0];
  }
}

// ============ kgmax (R8 verbatim): g[c] = max over 512 rows of gpart[512][1024]
__global__ __launch_bounds__(256) void kgmax(const float* __restrict__ gpart, float* __restrict__ g) {
  int t = blockIdx.x * 256 + threadIdx.x;  // 8192 threads
  int c = t & 1023, rg = t >> 10;
  const float* gp = gpart + (size_t)rg * 64 * 1024 + c;
  float m = 0.f;
#pragma unroll 8
  for (int r = 0; r < 64; ++r) m = fmaxf(m, gp[(size_t)r * 1024]);
  atomicMax((unsigned int*)(g + c), __float_as_uint(m));  // all values >= 0
}

// ============ kc5 (R8 verbatim): c5[c] = W5[c][64:1088] @ g + b5[c]
__global__ __launch_bounds__(256) void kc5(
    const float* __restrict__ W5, const float* __restrict__ b5,
    const float* __restrict__ g, float* __restrict__ c5) {
  int tid = threadIdx.x;
  int ci = tid >> 3, kg = tid & 7;
  int c = blockIdx.x * 32 + ci;
  const float* wrow = W5 + (size_t)c * 1088 + 64 + kg * 128;
  const float* gp = g + kg * 128;
  float acc = 0.f;
#pragma unroll 8
  for (int k = 0; k < 128; ++k) acc += wrow[k] * gp[k];
#pragma unroll
  for (int off = 1; off <= 4; off <<= 1) acc += __shfl_xor(acc, off);
  if (kg == 0) c5[c] = acc + b5[c];
}

// ======================================================================
// mega2 (bisect candidate): h2 -> z5 -> z6 -> z7 -> out, 64-pt blocks
// Internal contract (2 mi slots): octet idx = (kc*2+mi)*64+l;
//   point = mi*32+(l&31), channel = kc*16+(l>>5)*8+j.
// ======================================================================

struct Oct { bf16x8 h0, l0, h1, l1; };
__device__ __forceinline__ Oct epi_pack(const f32x16& accv, int hb) {
  float a[16], rcv[8];
#pragma unroll
  for (int r = 0; r < 16; ++r) a[r] = relu(accv[r]);
#pragma unroll
  for (int j = 0; j < 8; ++j) rcv[j] = __shfl_xor(hb ? a[j] : a[8 + j], 32);
  float o0[8], o1[8];
#pragma unroll
  for (int j = 0; j < 4; ++j) {
    o0[j]     = hb ? rcv[j]     : a[j];
    o0[4 + j] = hb ? a[8 + j]   : rcv[j];
    o1[j]     = hb ? rcv[4 + j] : a[4 + j];
    o1[4 + j] = hb ? a[12 + j]  : rcv[4 + j];
  }
  Oct o;
#pragma unroll
  for (int j = 0; j < 8; ++j) {
    bf16_t x0 = (bf16_t)o0[j]; o.h0[j] = x0; o.l0[j] = (bf16_t)(o0[j] - (float)x0);
    bf16_t x1 = (bf16_t)o1[j]; o.h1[j] = x1; o.l1[j] = (bf16_t)(o1[j] - (float)x1);
  }
  return o;
}

__device__ __forceinline__ void epi_store_lds(const Oct& o, bf16_t* H, bf16_t* L, int ob, int p31) {
  *(bf16x8*)(H + (ob + p31) * 8)      = o.h0;
  *(bf16x8*)(H + (ob + 32 + p31) * 8) = o.h1;
  *(bf16x8*)(L + (ob + p31) * 8)      = o.l0;
  *(bf16x8*)(L + (ob + 32 + p31) * 8) = o.l1;
}

__device__ __forceinline__ void binit2(f32x16 acc[2], const float* bias, int base, int hb) {
#pragma unroll
  for (int r = 0; r < 16; ++r) {
    float bv = bias[base + 8 * (r >> 2) + 4 * hb + (r & 3)];
    acc[0][r] = bv; acc[1][r] = bv;
  }
}

template <int NKC>
__device__ __forceinline__ void wgemm(const bf16_t* __restrict__ Wh, const bf16_t* __restrict__ Wl,
                                      int st, const bf16_t* act, int loOff, int lane,
                                      f32x16 acc[2]) {
#pragma unroll
  for (int kc = 0; kc < NKC; ++kc) {
    size_t wo = ((size_t)(st * NKC + kc) * 64 + lane) * 8;
    bf16x8 awh = *(const bf16x8*)(Wh + wo), awl = *(const bf16x8*)(Wl + wo);
    bf16x8 xh[2], xl[2];
#pragma unroll
    for (int mi = 0; mi < 2; ++mi) {
      const bf16_t* xp = act + ((kc * 2 + mi) * 64 + lane) * 8;
      xh[mi] = *(const bf16x8*)xp; xl[mi] = *(const bf16x8*)(xp + loOff);
    }
#pragma unroll
    for (int mi = 0; mi < 2; ++mi) acc[mi] = MFMA32(awh, xh[mi], acc[mi]);
#pragma unroll
    for (int mi = 0; mi < 2; ++mi) acc[mi] = MFMA32(awl, xh[mi], acc[mi]);
#pragma unroll
    for (int mi = 0; mi < 2; ++mi) acc[mi] = MFMA32(awh, xl[mi], acc[mi]);
  }
}

__global__ __launch_bounds__(256, 2) void mega2(
    const bf16_t* __restrict__ h2gh, const bf16_t* __restrict__ h2gl,
    const bf16_t* __restrict__ W5h, const bf16_t* __restrict__ W5l, const float* __restrict__ c5,
    const bf16_t* __restrict__ W6h, const bf16_t* __restrict__ W6l, const float* __restrict__ b6,
    const bf16_t* __restrict__ W7h, const bf16_t* __restrict__ W7l, const float* __restrict__ b7,
    const float* __restrict__ w8, const float* __restrict__ b8v, float* __restrict__ out) {
  // phase A: h2 pair [0,8192), z5buf pair [8192,24576). phase B: z6 pair [0,32768).
  __shared__ __align__(16) bf16_t smem[32768];
  __shared__ float sp[4][64];
  int tid = threadIdx.x, lane = tid & 63;
  int w = __builtin_amdgcn_readfirstlane(tid >> 6);
  int hb = lane >> 5, p31 = lane & 31;
  int b = blockIdx.x;
  int B = b >> 1, half = b & 1;   // R8 h2 layout: 128-pt block B, 64-pt half
  bf16_t* z5buf = smem + 8192;

  // stage h2: remap R8 octet ((B*4+kc)*4 + half*2 + mi2)*64+l -> internal (kc*2+mi2)*64+l
#pragma unroll
  for (int i = 0; i < 4; ++i) {
    int u = i * 256 + tid;             // [0,1024) staged octets (512 hi + 512 lo)
    int t = u >> 9, rem = u & 511;
    int kcmi = rem >> 6, l = rem & 63;
    int kc = kcmi >> 1, mi2 = kcmi & 1;
    size_t so = ((size_t)((B * 4 + kc) * 4 + half * 2 + mi2) * 64 + l) * 8;
    const bf16_t* src = (t ? h2gl : h2gh) + so;
    *(bf16x8*)(smem + t * 4096 + rem * 8) = *(const bf16x8*)src;
  }
  __syncthreads();

  // z6 accumulators: wave owns strips {2w, 2w+1} (64 ch) x 64 pts
  f32x16 z6a[2][2];
#pragma unroll
  for (int s = 0; s < 2; ++s)
#pragma unroll
    for (int r = 0; r < 16; ++r) {
      float bv = b6[(w * 2 + s) * 32 + 8 * (r >> 2) + 4 * hb + (r & 3)];
      z6a[s][0][r] = bv; z6a[s][1][r] = bv;
    }

  for (int g5 = 0; g5 < 4; ++g5) {
    // ---- L5 strip: z5 chans [(g5*4+w)*32, +32)
    int st5 = g5 * 4 + w;
    f32x16 a5[2];
    binit2(a5, c5, st5 * 32, hb);
    wgemm<4>(W5h, W5l, st5, smem, 4096, lane, a5);
    __syncthreads();  // prev group's L6 reads of z5buf complete
#pragma unroll
    for (int mi = 0; mi < 2; ++mi) {
      Oct o = epi_pack(a5[mi], hb);
      epi_store_lds(o, z5buf, z5buf + 8192, ((w * 2 + hb) * 2 + mi) * 64, p31);
    }
    __syncthreads();  // z5buf ready
    // ---- L6 partial accumulate over this 128-k chunk
#pragma unroll
    for (int kc = 0; kc < 8; ++kc) {
      bf16x8 awh[2], awl[2], xh[2], xl[2];
#pragma unroll
      for (int s = 0; s < 2; ++s) {
        size_t wo = ((size_t)((w * 2 + s) * 32 + g5 * 8 + kc) * 64 + lane) * 8;
        awh[s] = *(const bf16x8*)(W6h + wo);
        awl[s] = *(const bf16x8*)(W6l + wo);
      }
#pragma unroll
      for (int mi = 0; mi < 2; ++mi) {
        const bf16_t* xp = z5buf + ((kc * 2 + mi) * 64 + lane) * 8;
        xh[mi] = *(const bf16x8*)xp; xl[mi] = *(const bf16x8*)(xp + 8192);
      }
#pragma unroll
      for (int s = 0; s < 2; ++s)
#pragma unroll
        for (int mi = 0; mi < 2; ++mi) z6a[s][mi] = MFMA32(awh[s], xh[mi], z6a[s][mi]);
#pragma unroll
      for (int s = 0; s < 2; ++s)
#pragma unroll
        for (int mi = 0; mi < 2; ++mi) z6a[s][mi] = MFMA32(awl[s], xh[mi], z6a[s][mi]);
#pragma unroll
      for (int s = 0; s < 2; ++s)
#pragma unroll
        for (int mi = 0; mi < 2; ++mi) z6a[s][mi] = MFMA32(awh[s], xl[mi], z6a[s][mi]);
    }
  }
  __syncthreads();  // all phase-A reads done
  // ---- z6 epilogue -> smem [0,32768): hi [0,16384), lo [16384,32768)
#pragma unroll
  for (int s = 0; s < 2; ++s) {
    int kcb = (w * 2 + s) * 2 + hb;
#pragma unroll
    for (int mi = 0; mi < 2; ++mi) {
      Oct o = epi_pack(z6a[s][mi], hb);
      epi_store_lds(o, smem, smem + 16384, (kcb * 2 + mi) * 64, p31);
    }
  }
  __syncthreads();
  // ---- L7: wave strip w, K=256
  f32x16 a7[2];
  binit2(a7, b7, w * 32, hb);
  wgemm<16>(W7h, W7l, w, smem, 16384, lane, a7);
  // ---- L8: dot with w8
  float w8v[16];
#pragma unroll
  for (int r = 0; r < 16; ++r) w8v[r] = w8[w * 32 + 8 * (r >> 2) + 4 * hb + (r & 3)];
#pragma unroll
  for (int mi = 0; mi < 2; ++mi) {
    float s = 0.f;
#pragma unroll
    for (int r = 0; r < 16; ++r) s = fmaf(relu(a7[mi][r]), w8v[r], s);
    s += __shfl_xor(s, 32);
    if (hb == 0) sp[w][mi * 32 + p31] = s;
  }
  __syncthreads();
  if (tid < 64)
    out[b * 64 + tid] = sp[0][tid] + sp[1][tid] + sp[2][tid] + sp[3][tid] + b8v[0];
}

extern "C" void kernel_launch(void* const* d_in, const int* in_sizes, int n_in,
                              void* d_out, int out_size, void* d_ws, size_t ws_size,
                              hipStream_t stream) {
  const float* x  = (const float*)d_in[0];
  const float* W1 = (const float*)d_in[1];  const float* b1 = (const float*)d_in[2];
  const float* W2 = (const float*)d_in[3];  const float* b2 = (const float*)d_in[4];
  const float* W3 = (const float*)d_in[5];  const float* b3 = (const float*)d_in[6];
  const float* W4 = (const float*)d_in[7];  const float* b4 = (const float*)d_in[8];
  const float* W5 = (const float*)d_in[9];  const float* b5 = (const float*)d_in[10];
  const float* W6 = (const float*)d_in[11]; const float* b6 = (const float*)d_in[12];
  const float* W7 = (const float*)d_in[13]; const float* b7 = (const float*)d_in[14];
  const float* W8 = (const float*)d_in[15]; const float* b8 = (const float*)d_in[16];
  float* out = (float*)d_out;

  // Workspace overlays (R8 verbatim; z5/z6 regions now unused):
  //   h2 pair [128,136)+[136,144)  L2->mega2
  //   h1 pair [144,152)+[152,160)  k1a->L2
  //   y3 pair [144,160)+[160,176)  L3->L4  (over dead h1)
  //   gpart [208,210), g/c5 [210,..), weight frags after
  const size_t MB = 1ull << 20;
  char* ws = (char*)d_ws;
  bf16_t* h2h = (bf16_t*)(ws + 128 * MB);  bf16_t* h2l = (bf16_t*)(ws + 136 * MB);
  bf16_t* h1h = (bf16_t*)(ws + 144 * MB);  bf16_t* h1l = (bf16_t*)(ws + 152 * MB);
  bf16_t* y3h = (bf16_t*)(ws + 144 * MB);  bf16_t* y3l = (bf16_t*)(ws + 160 * MB);
  float* gpart = (float*)(ws + 208 * MB);
  float* g     = (float*)(ws + 210 * MB);
  float* c5    = (float*)(ws + 210 * MB + 4096);
  char* wb = ws + 210 * MB + 65536;
  bf16_t* W2h = (bf16_t*)(wb);             bf16_t* W2l = (bf16_t*)(wb + 8192);
  bf16_t* W3h = (bf16_t*)(wb + 16384);     bf16_t* W3l = (bf16_t*)(wb + 32768);
  bf16_t* W4h = (bf16_t*)(wb + 49152);     bf16_t* W4l = (bf16_t*)(wb + 311296);
  bf16_t* W5h = (bf16_t*)(wb + 573440);    bf16_t* W5l = (bf16_t*)(wb + 638976);
  bf16_t* W6h = (bf16_t*)(wb + 704512);    bf16_t* W6l = (bf16_t*)(wb + 966656);
  bf16_t* W7h = (bf16_t*)(wb + 1228800);   bf16_t* W7l = (bf16_t*)(wb + 1294336);

  hipMemsetAsync(g, 0, 1024 * sizeof(float), stream);  // max identity (relu outputs >= 0)

  PrepAll pa;
  pa.seg[0] = {W2, W2h, W2l, 64, 64, 2};
  pa.seg[1] = {W3, W3h, W3l, 64, 64, 4};
  pa.seg[2] = {W4, W4h, W4l, 128, 128, 64};
  pa.seg[3] = {W5, W5h, W5l, 1088, 64, 16};   // W5[:, :64]
  pa.seg[4] = {W6, W6h, W6l, 512, 512, 64};
  pa.seg[5] = {W7, W7h, W7l, 256, 256, 16};
  kprep<<<166, 256, 0, stream>>>(pa);

  k1a<<<256, 256, 0, stream>>>(x, W1, b1, h1h, h1l);
  gemmS<2, 64, 0><<<dim3(256, 1), 256, 0, stream>>>(
      h1h, h1l, W2h, W2l, b2, 4, h2h, h2l, nullptr, nullptr, nullptr);        // L2
  gemmS<1, 64, 0><<<dim3(512, 1), 256, 0, stream>>>(
      h2h, h2l, W3h, W3l, b3, 8, y3h, y3l, nullptr, nullptr, nullptr);        // L3
  gemmS<1, 128, 1><<<dim3(512, 8), 256, 0, stream>>>(
      y3h, y3l, W4h, W4l, b4, 0, nullptr, nullptr, gpart, nullptr, nullptr);  // L4 + max
  kgmax<<<32, 256, 0, stream>>>(gpart, g);
  kc5<<<16, 256, 0, stream>>>(W5, b5, g, c5);
  mega2<<<1024, 256, 0, stream>>>(h2h, h2l, W5h, W5l, c5, W6h, W6l, b6,
                                  W7h, W7l, b7, W8, b8, out);                 // L5..L8 fused
}